// Round 1
// baseline (884.970 us; speedup 1.0000x reference)
//
#include <hip/hip_runtime.h>
#include <math.h>

#define NN 1152
#define DD 64
#define NSK 2016
#define NB 16
#define NROWS (NB*1024)

// ---------------- K1: G = P^T P (64x64) ----------------
__global__ __launch_bounds__(64) void k_gram(const float* __restrict__ P, float* __restrict__ G){
  const int i = blockIdx.x, j = threadIdx.x;
  float acc = 0.f;
  #pragma unroll 4
  for (int n = 0; n < NN; ++n)
    acc = fmaf(P[n*DD + i], P[n*DD + j], acc);
  G[i*DD + j] = acc;
}

// ---------------- K2: v = silu(cond) @ W^T + bias ----------------
__global__ __launch_bounds__(256) void k_vproj(const float* __restrict__ cond, const float* __restrict__ W,
                                               const float* __restrict__ bias, float* __restrict__ v){
  const int q = blockIdx.x, tid = threadIdx.x;
  float acc[NB];
  #pragma unroll
  for (int b = 0; b < NB; ++b) acc[b] = 0.f;
  for (int c = tid; c < NN; c += 256){
    const float wv = W[q*NN + c];
    #pragma unroll
    for (int b = 0; b < NB; ++b){
      const float xv = cond[b*NN + c];
      const float s = xv / (1.f + __expf(-xv));
      acc[b] = fmaf(wv, s, acc[b]);
    }
  }
  __shared__ float red[256*17];
  #pragma unroll
  for (int b = 0; b < NB; ++b) red[tid*17 + b] = acc[b];
  __syncthreads();
  for (int off = 128; off > 0; off >>= 1){
    if (tid < off){
      #pragma unroll
      for (int b = 0; b < NB; ++b) red[tid*17 + b] += red[(tid+off)*17 + b];
    }
    __syncthreads();
  }
  if (tid < NB) v[tid*NSK + q] = red[tid] + bias[q];
}

// ---------------- K3: LAPACK signs (Gram-Householder) + CholeskyQR inverse ----------------
// Produces RinvS (64x64) such that U_np = P @ RinvS.
__global__ __launch_bounds__(64) void k_qrsign(const float* __restrict__ G, const float* __restrict__ P,
                                               float* __restrict__ RinvS){
  __shared__ float S1[DD*DD];   // Gres, then CT (=R_mgs, transposed-Cholesky)
  __shared__ float S2[DD*DD];   // Wt (top rows), then Rinv
  __shared__ float S3[DD*DD];   // Rm (R of sign process)
  __shared__ float ssign[DD];
  __shared__ float sc[4];
  const int j = threadIdx.x; // 0..63

  // Phase A: sign process. S1=Gres=G, S2=Wt=P[0:64,:]
  for (int r = 0; r < DD; ++r){
    S1[r*DD + j] = G[r*DD + j];
    S2[r*DD + j] = P[r*DD + j];
  }
  __syncthreads();
  for (int k = 0; k < DD; ++k){
    if (j == 0){
      const float nsq = S1[k*DD + k];
      const float ah  = S2[k*DD + k];
      const float beta = (ah >= 0.f) ? -sqrtf(nsq) : sqrtf(nsq);
      sc[0] = beta;
      sc[1] = 1.f / (beta * (beta - ah));
      sc[2] = 1.f / beta;
      S3[k*DD + k] = beta;
      ssign[k] = (beta > 0.f) ? 1.f : -1.f;
    }
    __syncthreads();
    const float beta = sc[0], c1 = sc[1], c2 = sc[2];
    if (j > k){
      const float wkj = S2[k*DD + j];
      const float dj = S1[k*DD + j] - beta * wkj;
      const float cj = dj * c1;
      S3[k*DD + j] = wkj + dj * c2;
      for (int r = k+1; r < DD; ++r)
        S2[r*DD + j] -= cj * S2[r*DD + k];
    }
    __syncthreads();
    if (j > k){
      const float rkj = S3[k*DD + j];
      for (int i = k+1; i < DD; ++i)
        S1[i*DD + j] -= S3[k*DD + i] * rkj;
    }
    __syncthreads();
  }

  // Phase B: Cholesky of G, stored transposed: S1[k][j] = L[j][k] = R_mgs[k][j]
  __syncthreads();
  for (int r = 0; r < DD; ++r) S1[r*DD + j] = G[r*DD + j];
  __syncthreads();
  for (int k = 0; k < DD; ++k){
    if (j == 0) S1[k*DD + k] = sqrtf(S1[k*DD + k]);
    __syncthreads();
    const float dk = S1[k*DD + k];
    if (j > k) S1[k*DD + j] /= dk;
    __syncthreads();
    const float ljk = (j > k) ? S1[k*DD + j] : 0.f;
    for (int c = k+1; c < DD; ++c){
      const float lck = S1[k*DD + c];
      if (j >= c) S1[c*DD + j] -= ljk * lck;
    }
    __syncthreads();
  }

  // Phase C: invert upper-triangular R_mgs (S1) into S2 (lane j = column j)
  __syncthreads();
  for (int i = 0; i < DD; ++i) S2[i*DD + j] = 0.f;
  S2[j*DD + j] = 1.f / S1[j*DD + j];
  for (int i = DD-2; i >= 0; --i){
    if (i < j){
      float ssum = 0.f;
      for (int l = i+1; l < DD; ++l){
        if (l <= j) ssum += S1[i*DD + l] * S2[l*DD + j];
      }
      S2[i*DD + j] = -ssum / S1[i*DD + i];
    }
  }
  __syncthreads();
  // Phase D: fold LAPACK signs into columns
  const float sj = ssign[j];
  for (int i = 0; i < DD; ++i)
    RinvS[i*DD + j] = S2[i*DD + j] * sj;
}

// ---------------- K4: U = P @ RinvS (1152x64) ----------------
__global__ __launch_bounds__(256) void k_formU(const float* __restrict__ P, const float* __restrict__ RinvS,
                                               float* __restrict__ U){
  __shared__ float Rs[DD*65];
  const int tid = threadIdx.x;
  const int d = tid & 63, rr = tid >> 6;
  #pragma unroll
  for (int ii = 0; ii < 16; ++ii)
    Rs[(rr + 4*ii)*65 + d] = RinvS[(rr + 4*ii)*DD + d];
  __syncthreads();
  const int n = blockIdx.x*4 + rr;
  float acc = 0.f;
  #pragma unroll 8
  for (int k = 0; k < DD; ++k)
    acc = fmaf(P[n*DD + k], Rs[k*65 + d], acc);
  U[n*DD + d] = acc;
}

// ---------------- K5: M = expm(A) - I per batch ----------------
__device__ __forceinline__ void mm64(const float* A, const float* B, float* C, int tid){
  const int c = tid & 63, r0 = tid >> 6; // 1024 threads: r0 0..15
  float acc[4] = {0.f,0.f,0.f,0.f};
  for (int k = 0; k < DD; ++k){
    const float bv = B[k*65 + c];
    #pragma unroll
    for (int q = 0; q < 4; ++q)
      acc[q] = fmaf(A[(r0 + 16*q)*65 + k], bv, acc[q]);
  }
  #pragma unroll
  for (int q = 0; q < 4; ++q)
    C[(r0 + 16*q)*65 + c] = acc[q];
}

__global__ __launch_bounds__(1024) void k_expm(const float* __restrict__ v, float* __restrict__ M){
  __shared__ float As[DD*65], Bs[DD*65], Xs[DD*65];
  __shared__ float ncol[DD];
  __shared__ float scl[1];
  __shared__ int ssh[1];
  float* Cs = As; // As dead once Bs built
  const int b = blockIdx.x, tid = threadIdx.x;
  for (int idx = tid; idx < DD*65; idx += 1024) As[idx] = 0.f;
  __syncthreads();
  // build skew A from v (row-major upper-tri ordering)
  for (int idx = tid; idx < NSK; idx += 1024){
    int i = (int)((127.0f - sqrtf(16129.0f - 8.0f*(float)idx)) * 0.5f);
    while (i*(127 - i)/2 > idx) --i;
    while ((i+1)*(127 - (i+1))/2 <= idx) ++i;
    const int jj = idx - i*(127 - i)/2 + i + 1;
    const float val = v[b*NSK + idx];
    As[i*65 + jj] = val;
    As[jj*65 + i] = -val;
  }
  __syncthreads();
  if (tid < DD){
    float s = 0.f;
    for (int r = 0; r < DD; ++r) s += fabsf(As[r*65 + tid]);
    ncol[tid] = s;
  }
  __syncthreads();
  if (tid == 0){
    float nrm = 0.f;
    for (int c = 0; c < DD; ++c) nrm = fmaxf(nrm, ncol[c]);
    int s = 0; float scale = 1.f;
    while (nrm > 0.5f && s < 40){ nrm *= 0.5f; scale *= 0.5f; ++s; }
    ssh[0] = s; scl[0] = scale;
  }
  __syncthreads();
  const float scale = scl[0];
  const int sq = ssh[0];
  for (int idx = tid; idx < DD*65; idx += 1024) Bs[idx] = As[idx]*scale;
  __syncthreads();
  // Horner: X = I + B/10
  for (int idx = tid; idx < DD*DD; idx += 1024){
    const int i = idx >> 6, jj = idx & 63;
    Xs[i*65 + jj] = Bs[i*65 + jj]*0.1f + (i == jj ? 1.f : 0.f);
  }
  __syncthreads();
  for (int t = 9; t >= 1; --t){
    mm64(Bs, Xs, Cs, tid);
    __syncthreads();
    const float invt = 1.f / (float)t;
    for (int idx = tid; idx < DD*DD; idx += 1024){
      const int i = idx >> 6, jj = idx & 63;
      Xs[i*65 + jj] = Cs[i*65 + jj]*invt + (i == jj ? 1.f : 0.f);
    }
    __syncthreads();
  }
  for (int r = 0; r < sq; ++r){
    mm64(Xs, Xs, Cs, tid);
    __syncthreads();
    for (int idx = tid; idx < DD*DD; idx += 1024){
      const int i = idx >> 6, jj = idx & 63;
      Xs[i*65 + jj] = Cs[i*65 + jj];
    }
    __syncthreads();
  }
  for (int idx = tid; idx < DD*DD; idx += 1024){
    const int i = idx >> 6, jj = idx & 63;
    M[b*DD*DD + idx] = Xs[i*65 + jj] - (i == jj ? 1.f : 0.f);
  }
}

// ---------------- K6: w = (x @ U) @ M, 64-row tiles ----------------
__global__ __launch_bounds__(256) void k_zw(const float* __restrict__ x, const float* __restrict__ U,
                                            const float* __restrict__ Mg, float* __restrict__ wbuf){
  __shared__ float xs[64*33];
  __shared__ float Us[32*65];
  __shared__ float zs[64*65];
  __shared__ float Ms[64*65];
  const int tid = threadIdx.x;
  const int row0 = blockIdx.x * 64;
  const int bb = row0 >> 10;           // 1024 rows per batch
  const int tx = tid & 15, ty = tid >> 4;
  const int kk = tid & 31, lr = tid >> 5;
  const int du = tid & 63, ku = tid >> 6;
  float acc[4][4];
  #pragma unroll
  for (int i=0;i<4;++i){
    #pragma unroll
    for (int jq=0;jq<4;++jq) acc[i][jq]=0.f;
  }
  for (int kc = 0; kc < NN; kc += 32){
    __syncthreads();
    #pragma unroll
    for (int ii = 0; ii < 8; ++ii)
      xs[(lr + 8*ii)*33 + kk] = x[(row0 + lr + 8*ii)*NN + kc + kk];
    #pragma unroll
    for (int ii = 0; ii < 8; ++ii)
      Us[(ku + 4*ii)*65 + du] = U[(kc + ku + 4*ii)*DD + du];
    __syncthreads();
    #pragma unroll 4
    for (int k = 0; k < 32; ++k){
      float a[4], bv[4];
      #pragma unroll
      for (int i=0;i<4;++i) a[i] = xs[(ty*4+i)*33 + k];
      #pragma unroll
      for (int jq=0;jq<4;++jq) bv[jq] = Us[k*65 + tx*4 + jq];
      #pragma unroll
      for (int i=0;i<4;++i){
        #pragma unroll
        for (int jq=0;jq<4;++jq) acc[i][jq] = fmaf(a[i], bv[jq], acc[i][jq]);
      }
    }
  }
  __syncthreads();
  #pragma unroll
  for (int i=0;i<4;++i){
    #pragma unroll
    for (int jq=0;jq<4;++jq) zs[(ty*4+i)*65 + tx*4 + jq] = acc[i][jq];
  }
  #pragma unroll
  for (int ii = 0; ii < 16; ++ii)
    Ms[(ku + 4*ii)*65 + du] = Mg[bb*4096 + (ku + 4*ii)*DD + du];
  __syncthreads();
  #pragma unroll
  for (int i=0;i<4;++i){
    #pragma unroll
    for (int jq=0;jq<4;++jq) acc[i][jq]=0.f;
  }
  for (int d = 0; d < DD; ++d){
    float a[4], bv[4];
    #pragma unroll
    for (int i=0;i<4;++i) a[i] = zs[(ty*4+i)*65 + d];
    #pragma unroll
    for (int jq=0;jq<4;++jq) bv[jq] = Ms[d*65 + tx*4 + jq];
    #pragma unroll
    for (int i=0;i<4;++i){
      #pragma unroll
      for (int jq=0;jq<4;++jq) acc[i][jq] = fmaf(a[i], bv[jq], acc[i][jq]);
    }
  }
  #pragma unroll
  for (int i=0;i<4;++i){
    float4 wv = make_float4(acc[i][0], acc[i][1], acc[i][2], acc[i][3]);
    *(float4*)&wbuf[(row0 + ty*4 + i)*DD + tx*4] = wv;
  }
}

// ---------------- K7: out = x + w @ U^T ----------------
__global__ __launch_bounds__(256) void k_out(const float* __restrict__ x, const float* __restrict__ wbuf,
                                             const float* __restrict__ U, float* __restrict__ out){
  __shared__ float wts[64*65];
  __shared__ float Ut[64*65];
  const int tid = threadIdx.x;
  const int n0 = blockIdx.x * 64;
  const int row0 = blockIdx.y * 64;
  const int tx = tid & 15, ty = tid >> 4;
  const int du = tid & 63, ku = tid >> 6;
  #pragma unroll
  for (int ii = 0; ii < 16; ++ii){
    wts[(ku + 4*ii)*65 + du] = wbuf[(row0 + ku + 4*ii)*DD + du];
    Ut[(ku + 4*ii)*65 + du]  = U[(n0 + ku + 4*ii)*DD + du];
  }
  __syncthreads();
  float acc[4][4];
  #pragma unroll
  for (int i=0;i<4;++i){
    #pragma unroll
    for (int jq=0;jq<4;++jq) acc[i][jq]=0.f;
  }
  for (int d = 0; d < DD; ++d){
    float a[4], bv[4];
    #pragma unroll
    for (int i=0;i<4;++i) a[i] = wts[(ty*4+i)*65 + d];
    #pragma unroll
    for (int jq=0;jq<4;++jq) bv[jq] = Ut[(tx*4+jq)*65 + d];
    #pragma unroll
    for (int i=0;i<4;++i){
      #pragma unroll
      for (int jq=0;jq<4;++jq) acc[i][jq] = fmaf(a[i], bv[jq], acc[i][jq]);
    }
  }
  #pragma unroll
  for (int i = 0; i < 4; ++i){
    const int r = row0 + ty*4 + i;
    const float4 xv = *(const float4*)&x[r*NN + n0 + tx*4];
    float4 ov;
    ov.x = xv.x + acc[i][0];
    ov.y = xv.y + acc[i][1];
    ov.z = xv.z + acc[i][2];
    ov.w = xv.w + acc[i][3];
    *(float4*)&out[r*NN + n0 + tx*4] = ov;
  }
}

extern "C" void kernel_launch(void* const* d_in, const int* in_sizes, int n_in,
                              void* d_out, int out_size, void* d_ws, size_t ws_size,
                              hipStream_t stream) {
  const float* x    = (const float*)d_in[0];
  const float* cond = (const float*)d_in[1];
  const float* P    = (const float*)d_in[2];
  const float* W    = (const float*)d_in[3];
  const float* bias = (const float*)d_in[4];
  float* out = (float*)d_out;
  float* ws  = (float*)d_ws;

  float* U     = ws;               // 73728
  float* G     = ws + 73728;       // 4096
  float* RinvS = ws + 77824;       // 4096
  float* v     = ws + 81920;       // 32256
  float* M     = ws + 114176;      // 65536
  float* wbuf  = ws + 179712;      // 1048576
  // total ~4.7 MB

  hipLaunchKernelGGL(k_gram,  dim3(64),   dim3(64),  0, stream, P, G);
  hipLaunchKernelGGL(k_vproj, dim3(NSK),  dim3(256), 0, stream, cond, W, bias, v);
  hipLaunchKernelGGL(k_qrsign,dim3(1),    dim3(64),  0, stream, G, P, RinvS);
  hipLaunchKernelGGL(k_formU, dim3(288),  dim3(256), 0, stream, P, RinvS, U);
  hipLaunchKernelGGL(k_expm,  dim3(NB),   dim3(1024),0, stream, v, M);
  hipLaunchKernelGGL(k_zw,    dim3(NROWS/64), dim3(256), 0, stream, x, U, M, wbuf);
  hipLaunchKernelGGL(k_out,   dim3(NN/64, NROWS/64), dim3(256), 0, stream, x, wbuf, U, out);
}

// Round 2
// 577.795 us; speedup vs baseline: 1.5316x; 1.5316x over previous
//
#include <hip/hip_runtime.h>
#include <math.h>

#define NN 1152
#define DD 64
#define NSK 2016
#define NB 16
#define NROWS (NB*1024)

// ---------------- K1: G = P^T P (64x64) ----------------
__global__ __launch_bounds__(64) void k_gram(const float* __restrict__ P, float* __restrict__ G){
  const int i = blockIdx.x, j = threadIdx.x;
  float acc = 0.f;
  #pragma unroll 4
  for (int n = 0; n < NN; ++n)
    acc = fmaf(P[n*DD + i], P[n*DD + j], acc);
  G[i*DD + j] = acc;
}

// ---------------- K2: v = silu(cond) @ W^T + bias ----------------
__global__ __launch_bounds__(256) void k_vproj(const float* __restrict__ cond, const float* __restrict__ W,
                                               const float* __restrict__ bias, float* __restrict__ v){
  const int q = blockIdx.x, tid = threadIdx.x;
  float acc[NB];
  #pragma unroll
  for (int b = 0; b < NB; ++b) acc[b] = 0.f;
  for (int c = tid; c < NN; c += 256){
    const float wv = W[q*NN + c];
    #pragma unroll
    for (int b = 0; b < NB; ++b){
      const float xv = cond[b*NN + c];
      const float s = xv / (1.f + __expf(-xv));
      acc[b] = fmaf(wv, s, acc[b]);
    }
  }
  __shared__ float red[256*17];
  #pragma unroll
  for (int b = 0; b < NB; ++b) red[tid*17 + b] = acc[b];
  __syncthreads();
  for (int off = 128; off > 0; off >>= 1){
    if (tid < off){
      #pragma unroll
      for (int b = 0; b < NB; ++b) red[tid*17 + b] += red[(tid+off)*17 + b];
    }
    __syncthreads();
  }
  if (tid < NB) v[tid*NSK + q] = red[tid] + bias[q];
}

// ---------------- K3: LAPACK-convention R via Gram-Householder recursion ----------------
// Produces R (64x64 upper, signed diag exactly as np.linalg.qr) such that U_np = P @ R^{-1}.
// Parallel: 256 threads; per k-step the two rank-1 updates (Wt: top-64 rows of the
// working matrix; Gres: residual Gram) are spread over all threads.
__global__ __launch_bounds__(256) void k_qr(const float* __restrict__ G, const float* __restrict__ P,
                                            float* __restrict__ Rout){
  __shared__ float Gres[DD*DD];
  __shared__ float Wt[DD*DD];
  __shared__ float R[DD*DD];
  __shared__ float cvec[DD];
  const int tid = threadIdx.x;
  for (int idx = tid; idx < DD*DD; idx += 256){
    Gres[idx] = G[idx];
    Wt[idx]   = P[idx];   // rows 0..63 of P are the first 4096 elems (row-major)
    R[idx]    = 0.f;
  }
  __syncthreads();
  for (int k = 0; k < DD; ++k){
    if (tid < DD){
      const int j = tid;
      const float ah  = Wt[k*DD + k];       // broadcast reads
      const float nsq = Gres[k*DD + k];
      const float beta = (ah >= 0.f) ? -sqrtf(nsq) : sqrtf(nsq);
      if (j == k) R[k*DD + k] = beta;
      if (j > k){
        const float wkj = Wt[k*DD + j];
        const float dj  = Gres[k*DD + j] - beta*wkj;
        cvec[j] = dj / (beta*(beta - ah));
        R[k*DD + j] = wkj + dj/beta;
      }
    }
    __syncthreads();
    for (int idx = tid; idx < DD*DD; idx += 256){
      const int i = idx >> 6, j = idx & 63;
      if (i > k && j > k){
        Wt[idx]   = fmaf(-cvec[j],     Wt[i*DD + k], Wt[idx]);    // col-k read = broadcast
        Gres[idx] = fmaf(-R[k*DD + i], R[k*DD + j],  Gres[idx]);  // row-k reads = broadcast
      }
    }
    __syncthreads();
  }
  for (int idx = tid; idx < DD*DD; idx += 256)
    Rout[idx] = R[idx];
}

// ---------------- K4: U = P @ R^{-1} via per-row triangular solve u.R = p ----------------
__global__ __launch_bounds__(64) void k_solveU(const float* __restrict__ P, const float* __restrict__ Rg,
                                               float* __restrict__ U){
  __shared__ float Rs[DD*DD];
  __shared__ float Ps[DD*65];
  __shared__ float rd[DD];
  const int tid = threadIdx.x;
  const int n0 = blockIdx.x * DD;
  for (int r = 0; r < DD; ++r){
    Rs[r*DD + tid] = Rg[r*DD + tid];
    Ps[r*65 + tid] = P[(n0 + r)*DD + tid];
  }
  rd[tid] = 1.f / Rg[tid*DD + tid];
  __syncthreads();
  float u[DD];
  #pragma unroll
  for (int j = 0; j < DD; ++j){
    float s0 = Ps[tid*65 + j], s1 = 0.f;
    #pragma unroll
    for (int l = 0; l + 1 < j; l += 2){
      s0 = fmaf(-u[l],   Rs[l*DD + j],     s0);   // Rs reads: same addr all lanes = broadcast
      s1 = fmaf(-u[l+1], Rs[(l+1)*DD + j], s1);
    }
    if (j & 1) s0 = fmaf(-u[j-1], Rs[(j-1)*DD + j], s0);
    u[j] = (s0 + s1) * rd[j];
  }
  __syncthreads();
  #pragma unroll
  for (int j = 0; j < DD; ++j) Ps[tid*65 + j] = u[j];
  __syncthreads();
  for (int r = 0; r < DD; ++r)
    U[(n0 + r)*DD + tid] = Ps[r*65 + tid];
}

// ---------------- K5: M = expm(A) - I per batch ----------------
__device__ __forceinline__ void mm64(const float* A, const float* B, float* C, int tid){
  const int c = tid & 63, r0 = tid >> 6; // 1024 threads: r0 0..15
  float acc[4] = {0.f,0.f,0.f,0.f};
  for (int k = 0; k < DD; ++k){
    const float bv = B[k*65 + c];
    #pragma unroll
    for (int q = 0; q < 4; ++q)
      acc[q] = fmaf(A[(r0 + 16*q)*65 + k], bv, acc[q]);
  }
  #pragma unroll
  for (int q = 0; q < 4; ++q)
    C[(r0 + 16*q)*65 + c] = acc[q];
}

__global__ __launch_bounds__(1024) void k_expm(const float* __restrict__ v, float* __restrict__ M){
  __shared__ float As[DD*65], Bs[DD*65], Xs[DD*65];
  __shared__ float ncol[DD];
  __shared__ float scl[1];
  __shared__ int ssh[1];
  float* Cs = As; // As dead once Bs built
  const int b = blockIdx.x, tid = threadIdx.x;
  for (int idx = tid; idx < DD*65; idx += 1024) As[idx] = 0.f;
  __syncthreads();
  // build skew A from v (row-major upper-tri ordering)
  for (int idx = tid; idx < NSK; idx += 1024){
    int i = (int)((127.0f - sqrtf(16129.0f - 8.0f*(float)idx)) * 0.5f);
    while (i*(127 - i)/2 > idx) --i;
    while ((i+1)*(127 - (i+1))/2 <= idx) ++i;
    const int jj = idx - i*(127 - i)/2 + i + 1;
    const float val = v[b*NSK + idx];
    As[i*65 + jj] = val;
    As[jj*65 + i] = -val;
  }
  __syncthreads();
  if (tid < DD){
    float s = 0.f;
    for (int r = 0; r < DD; ++r) s += fabsf(As[r*65 + tid]);
    ncol[tid] = s;
  }
  __syncthreads();
  if (tid == 0){
    float nrm = 0.f;
    for (int c = 0; c < DD; ++c) nrm = fmaxf(nrm, ncol[c]);
    int s = 0; float scale = 1.f;
    while (nrm > 0.5f && s < 40){ nrm *= 0.5f; scale *= 0.5f; ++s; }
    ssh[0] = s; scl[0] = scale;
  }
  __syncthreads();
  const float scale = scl[0];
  const int sq = ssh[0];
  for (int idx = tid; idx < DD*65; idx += 1024) Bs[idx] = As[idx]*scale;
  __syncthreads();
  // Horner: X = I + B/10
  for (int idx = tid; idx < DD*DD; idx += 1024){
    const int i = idx >> 6, jj = idx & 63;
    Xs[i*65 + jj] = Bs[i*65 + jj]*0.1f + (i == jj ? 1.f : 0.f);
  }
  __syncthreads();
  for (int t = 9; t >= 1; --t){
    mm64(Bs, Xs, Cs, tid);
    __syncthreads();
    const float invt = 1.f / (float)t;
    for (int idx = tid; idx < DD*DD; idx += 1024){
      const int i = idx >> 6, jj = idx & 63;
      Xs[i*65 + jj] = Cs[i*65 + jj]*invt + (i == jj ? 1.f : 0.f);
    }
    __syncthreads();
  }
  for (int r = 0; r < sq; ++r){
    mm64(Xs, Xs, Cs, tid);
    __syncthreads();
    for (int idx = tid; idx < DD*DD; idx += 1024){
      const int i = idx >> 6, jj = idx & 63;
      Xs[i*65 + jj] = Cs[i*65 + jj];
    }
    __syncthreads();
  }
  for (int idx = tid; idx < DD*DD; idx += 1024){
    const int i = idx >> 6, jj = idx & 63;
    M[b*DD*DD + idx] = Xs[i*65 + jj] - (i == jj ? 1.f : 0.f);
  }
}

// ---------------- K6: w = (x @ U) @ M, 64-row tiles ----------------
__global__ __launch_bounds__(256) void k_zw(const float* __restrict__ x, const float* __restrict__ U,
                                            const float* __restrict__ Mg, float* __restrict__ wbuf){
  __shared__ float xs[64*33];
  __shared__ float Us[32*65];
  __shared__ float zs[64*65];
  __shared__ float Ms[64*65];
  const int tid = threadIdx.x;
  const int row0 = blockIdx.x * 64;
  const int bb = row0 >> 10;           // 1024 rows per batch
  const int tx = tid & 15, ty = tid >> 4;
  const int kk = tid & 31, lr = tid >> 5;
  const int du = tid & 63, ku = tid >> 6;
  float acc[4][4];
  #pragma unroll
  for (int i=0;i<4;++i){
    #pragma unroll
    for (int jq=0;jq<4;++jq) acc[i][jq]=0.f;
  }
  for (int kc = 0; kc < NN; kc += 32){
    __syncthreads();
    #pragma unroll
    for (int ii = 0; ii < 8; ++ii)
      xs[(lr + 8*ii)*33 + kk] = x[(row0 + lr + 8*ii)*NN + kc + kk];
    #pragma unroll
    for (int ii = 0; ii < 8; ++ii)
      Us[(ku + 4*ii)*65 + du] = U[(kc + ku + 4*ii)*DD + du];
    __syncthreads();
    #pragma unroll 4
    for (int k = 0; k < 32; ++k){
      float a[4], bv[4];
      #pragma unroll
      for (int i=0;i<4;++i) a[i] = xs[(ty*4+i)*33 + k];
      #pragma unroll
      for (int jq=0;jq<4;++jq) bv[jq] = Us[k*65 + tx*4 + jq];
      #pragma unroll
      for (int i=0;i<4;++i){
        #pragma unroll
        for (int jq=0;jq<4;++jq) acc[i][jq] = fmaf(a[i], bv[jq], acc[i][jq]);
      }
    }
  }
  __syncthreads();
  #pragma unroll
  for (int i=0;i<4;++i){
    #pragma unroll
    for (int jq=0;jq<4;++jq) zs[(ty*4+i)*65 + tx*4 + jq] = acc[i][jq];
  }
  #pragma unroll
  for (int ii = 0; ii < 16; ++ii)
    Ms[(ku + 4*ii)*65 + du] = Mg[bb*4096 + (ku + 4*ii)*DD + du];
  __syncthreads();
  #pragma unroll
  for (int i=0;i<4;++i){
    #pragma unroll
    for (int jq=0;jq<4;++jq) acc[i][jq]=0.f;
  }
  for (int d = 0; d < DD; ++d){
    float a[4], bv[4];
    #pragma unroll
    for (int i=0;i<4;++i) a[i] = zs[(ty*4+i)*65 + d];
    #pragma unroll
    for (int jq=0;jq<4;++jq) bv[jq] = Ms[d*65 + tx*4 + jq];
    #pragma unroll
    for (int i=0;i<4;++i){
      #pragma unroll
      for (int jq=0;jq<4;++jq) acc[i][jq] = fmaf(a[i], bv[jq], acc[i][jq]);
    }
  }
  #pragma unroll
  for (int i=0;i<4;++i){
    float4 wv = make_float4(acc[i][0], acc[i][1], acc[i][2], acc[i][3]);
    *(float4*)&wbuf[(row0 + ty*4 + i)*DD + tx*4] = wv;
  }
}

// ---------------- K7: out = x + w @ U^T ----------------
__global__ __launch_bounds__(256) void k_out(const float* __restrict__ x, const float* __restrict__ wbuf,
                                             const float* __restrict__ U, float* __restrict__ out){
  __shared__ float wts[64*65];
  __shared__ float Ut[64*65];
  const int tid = threadIdx.x;
  const int n0 = blockIdx.x * 64;
  const int row0 = blockIdx.y * 64;
  const int tx = tid & 15, ty = tid >> 4;
  const int du = tid & 63, ku = tid >> 6;
  #pragma unroll
  for (int ii = 0; ii < 16; ++ii){
    wts[(ku + 4*ii)*65 + du] = wbuf[(row0 + ku + 4*ii)*DD + du];
    Ut[(ku + 4*ii)*65 + du]  = U[(n0 + ku + 4*ii)*DD + du];
  }
  __syncthreads();
  float acc[4][4];
  #pragma unroll
  for (int i=0;i<4;++i){
    #pragma unroll
    for (int jq=0;jq<4;++jq) acc[i][jq]=0.f;
  }
  for (int d = 0; d < DD; ++d){
    float a[4], bv[4];
    #pragma unroll
    for (int i=0;i<4;++i) a[i] = wts[(ty*4+i)*65 + d];
    #pragma unroll
    for (int jq=0;jq<4;++jq) bv[jq] = Ut[(tx*4+jq)*65 + d];
    #pragma unroll
    for (int i=0;i<4;++i){
      #pragma unroll
      for (int jq=0;jq<4;++jq) acc[i][jq] = fmaf(a[i], bv[jq], acc[i][jq]);
    }
  }
  #pragma unroll
  for (int i = 0; i < 4; ++i){
    const int r = row0 + ty*4 + i;
    const float4 xv = *(const float4*)&x[r*NN + n0 + tx*4];
    float4 ov;
    ov.x = xv.x + acc[i][0];
    ov.y = xv.y + acc[i][1];
    ov.z = xv.z + acc[i][2];
    ov.w = xv.w + acc[i][3];
    *(float4*)&out[r*NN + n0 + tx*4] = ov;
  }
}

extern "C" void kernel_launch(void* const* d_in, const int* in_sizes, int n_in,
                              void* d_out, int out_size, void* d_ws, size_t ws_size,
                              hipStream_t stream) {
  const float* x    = (const float*)d_in[0];
  const float* cond = (const float*)d_in[1];
  const float* P    = (const float*)d_in[2];
  const float* W    = (const float*)d_in[3];
  const float* bias = (const float*)d_in[4];
  float* out = (float*)d_out;
  float* ws  = (float*)d_ws;

  float* U    = ws;               // 73728
  float* G    = ws + 73728;       // 4096
  float* Rbuf = ws + 77824;       // 4096
  float* v    = ws + 81920;       // 32256
  float* M    = ws + 114176;      // 65536
  float* wbuf = ws + 179712;      // 1048576

  hipLaunchKernelGGL(k_gram,   dim3(64),       dim3(64),  0, stream, P, G);
  hipLaunchKernelGGL(k_vproj,  dim3(NSK),      dim3(256), 0, stream, cond, W, bias, v);
  hipLaunchKernelGGL(k_qr,     dim3(1),        dim3(256), 0, stream, G, P, Rbuf);
  hipLaunchKernelGGL(k_solveU, dim3(NN/DD),    dim3(64),  0, stream, P, Rbuf, U);
  hipLaunchKernelGGL(k_expm,   dim3(NB),       dim3(1024),0, stream, v, M);
  hipLaunchKernelGGL(k_zw,     dim3(NROWS/64), dim3(256), 0, stream, x, U, M, wbuf);
  hipLaunchKernelGGL(k_out,    dim3(NN/64, NROWS/64), dim3(256), 0, stream, x, wbuf, U, out);
}

// Round 3
// 472.482 us; speedup vs baseline: 1.8730x; 1.2229x over previous
//
#include <hip/hip_runtime.h>
#include <math.h>

#define NN 1152
#define DD 64
#define NSK 2016
#define NB 16
#define NROWS (NB*1024)
#define GPARTS 18

// ---------------- K1: partial Gram. Block p: Gpart[p] = P[64p:64p+64,:]^T @ P[...] ----------------
__global__ __launch_bounds__(256) void k_gram(const float* __restrict__ P, float* __restrict__ Gpart){
  __shared__ float Ps[64*68];
  const int tid = threadIdx.x;
  const int n0 = blockIdx.x * 64;
  const int lr = tid >> 4, lc = (tid & 15) * 4;
  #pragma unroll
  for (int ii = 0; ii < 4; ++ii){
    const float4 pv = *(const float4*)&P[(n0 + lr + 16*ii)*DD + lc];
    *(float4*)&Ps[(lr + 16*ii)*68 + lc] = pv;
  }
  __syncthreads();
  const int ti = tid >> 4, tj = tid & 15;
  float acc[4][4];
  #pragma unroll
  for (int i=0;i<4;++i){
    #pragma unroll
    for (int j=0;j<4;++j) acc[i][j]=0.f;
  }
  for (int r = 0; r < 64; ++r){
    const float4 a = *(const float4*)&Ps[r*68 + ti*4];
    const float4 b = *(const float4*)&Ps[r*68 + tj*4];
    const float av[4] = {a.x,a.y,a.z,a.w};
    const float bv[4] = {b.x,b.y,b.z,b.w};
    #pragma unroll
    for (int i=0;i<4;++i){
      #pragma unroll
      for (int j=0;j<4;++j) acc[i][j] = fmaf(av[i], bv[j], acc[i][j]);
    }
  }
  float* g = &Gpart[blockIdx.x*DD*DD];
  #pragma unroll
  for (int i=0;i<4;++i){
    float4 ov = make_float4(acc[i][0], acc[i][1], acc[i][2], acc[i][3]);
    *(float4*)&g[(ti*4+i)*DD + tj*4] = ov;
  }
}

// ---------------- K2: v = silu(cond) @ W^T + bias ----------------
__global__ __launch_bounds__(256) void k_vproj(const float* __restrict__ cond, const float* __restrict__ W,
                                               const float* __restrict__ bias, float* __restrict__ v){
  const int q = blockIdx.x, tid = threadIdx.x;
  float acc[NB];
  #pragma unroll
  for (int b = 0; b < NB; ++b) acc[b] = 0.f;
  for (int c = tid; c < NN; c += 256){
    const float wv = W[q*NN + c];
    #pragma unroll
    for (int b = 0; b < NB; ++b){
      const float xv = cond[b*NN + c];
      const float s = xv / (1.f + __expf(-xv));
      acc[b] = fmaf(wv, s, acc[b]);
    }
  }
  __shared__ float red[256*17];
  #pragma unroll
  for (int b = 0; b < NB; ++b) red[tid*17 + b] = acc[b];
  __syncthreads();
  for (int off = 128; off > 0; off >>= 1){
    if (tid < off){
      #pragma unroll
      for (int b = 0; b < NB; ++b) red[tid*17 + b] += red[(tid+off)*17 + b];
    }
    __syncthreads();
  }
  if (tid < NB) v[tid*NSK + q] = red[tid] + bias[q];
}

// ---------------- K3: LAPACK-convention R via Gram-Householder recursion ----------------
__global__ __launch_bounds__(256) void k_qr(const float* __restrict__ Gpart, const float* __restrict__ P,
                                            float* __restrict__ Rout){
  __shared__ float Gres[DD*DD];
  __shared__ float Wt[DD*DD];
  __shared__ float R[DD*DD];
  __shared__ float cvec[DD];
  const int tid = threadIdx.x;
  for (int idx = tid; idx < DD*DD; idx += 256){
    float g = 0.f;
    #pragma unroll
    for (int p = 0; p < GPARTS; ++p) g += Gpart[p*DD*DD + idx];
    Gres[idx] = g;
    Wt[idx]   = P[idx];   // rows 0..63 of P
    R[idx]    = 0.f;
  }
  __syncthreads();
  for (int k = 0; k < DD; ++k){
    if (tid < DD){
      const int j = tid;
      const float ah  = Wt[k*DD + k];
      const float nsq = Gres[k*DD + k];
      const float beta = (ah >= 0.f) ? -sqrtf(nsq) : sqrtf(nsq);
      if (j == k) R[k*DD + k] = beta;
      if (j > k){
        const float wkj = Wt[k*DD + j];
        const float dj  = Gres[k*DD + j] - beta*wkj;
        cvec[j] = dj / (beta*(beta - ah));
        R[k*DD + j] = wkj + dj/beta;
      }
    }
    __syncthreads();
    for (int idx = tid; idx < DD*DD; idx += 256){
      const int i = idx >> 6, j = idx & 63;
      if (i > k && j > k){
        Wt[idx]   = fmaf(-cvec[j],     Wt[i*DD + k], Wt[idx]);
        Gres[idx] = fmaf(-R[k*DD + i], R[k*DD + j],  Gres[idx]);
      }
    }
    __syncthreads();
  }
  for (int idx = tid; idx < DD*DD; idx += 256)
    Rout[idx] = R[idx];
}

// ---------------- K4: U = P @ R^{-1} via per-row triangular solve u.R = p ----------------
__global__ __launch_bounds__(64) void k_solveU(const float* __restrict__ P, const float* __restrict__ Rg,
                                               float* __restrict__ U){
  __shared__ float Rs[DD*DD];
  __shared__ float Ps[DD*65];
  __shared__ float rd[DD];
  const int tid = threadIdx.x;
  const int n0 = blockIdx.x * DD;
  for (int r = 0; r < DD; ++r){
    Rs[r*DD + tid] = Rg[r*DD + tid];
    Ps[r*65 + tid] = P[(n0 + r)*DD + tid];
  }
  rd[tid] = 1.f / Rg[tid*DD + tid];
  __syncthreads();
  float u[DD];
  #pragma unroll
  for (int j = 0; j < DD; ++j){
    float s0 = Ps[tid*65 + j], s1 = 0.f;
    #pragma unroll
    for (int l = 0; l + 1 < j; l += 2){
      s0 = fmaf(-u[l],   Rs[l*DD + j],     s0);
      s1 = fmaf(-u[l+1], Rs[(l+1)*DD + j], s1);
    }
    if (j & 1) s0 = fmaf(-u[j-1], Rs[(j-1)*DD + j], s0);
    u[j] = (s0 + s1) * rd[j];
  }
  __syncthreads();
  #pragma unroll
  for (int j = 0; j < DD; ++j) Ps[tid*65 + j] = u[j];
  __syncthreads();
  for (int r = 0; r < DD; ++r)
    U[(n0 + r)*DD + tid] = Ps[r*65 + tid];
}

// ---------------- K5: M = expm(A) - I per batch ----------------
__device__ __forceinline__ void mm64(const float* A, const float* B, float* C, int tid){
  const int c = tid & 63, r0 = tid >> 6;
  float acc[4] = {0.f,0.f,0.f,0.f};
  for (int k = 0; k < DD; ++k){
    const float bv = B[k*65 + c];
    #pragma unroll
    for (int q = 0; q < 4; ++q)
      acc[q] = fmaf(A[(r0 + 16*q)*65 + k], bv, acc[q]);
  }
  #pragma unroll
  for (int q = 0; q < 4; ++q)
    C[(r0 + 16*q)*65 + c] = acc[q];
}

__global__ __launch_bounds__(1024) void k_expm(const float* __restrict__ v, float* __restrict__ M){
  __shared__ float As[DD*65], Bs[DD*65], Xs[DD*65];
  __shared__ float ncol[DD];
  __shared__ float scl[1];
  __shared__ int ssh[1];
  float* Cs = As;
  const int b = blockIdx.x, tid = threadIdx.x;
  for (int idx = tid; idx < DD*65; idx += 1024) As[idx] = 0.f;
  __syncthreads();
  for (int idx = tid; idx < NSK; idx += 1024){
    int i = (int)((127.0f - sqrtf(16129.0f - 8.0f*(float)idx)) * 0.5f);
    while (i*(127 - i)/2 > idx) --i;
    while ((i+1)*(127 - (i+1))/2 <= idx) ++i;
    const int jj = idx - i*(127 - i)/2 + i + 1;
    const float val = v[b*NSK + idx];
    As[i*65 + jj] = val;
    As[jj*65 + i] = -val;
  }
  __syncthreads();
  if (tid < DD){
    float s = 0.f;
    for (int r = 0; r < DD; ++r) s += fabsf(As[r*65 + tid]);
    ncol[tid] = s;
  }
  __syncthreads();
  if (tid == 0){
    float nrm = 0.f;
    for (int c = 0; c < DD; ++c) nrm = fmaxf(nrm, ncol[c]);
    int s = 0; float scale = 1.f;
    while (nrm > 0.5f && s < 40){ nrm *= 0.5f; scale *= 0.5f; ++s; }
    ssh[0] = s; scl[0] = scale;
  }
  __syncthreads();
  const float scale = scl[0];
  const int sq = ssh[0];
  for (int idx = tid; idx < DD*65; idx += 1024) Bs[idx] = As[idx]*scale;
  __syncthreads();
  for (int idx = tid; idx < DD*DD; idx += 1024){
    const int i = idx >> 6, jj = idx & 63;
    Xs[i*65 + jj] = Bs[i*65 + jj]*0.1f + (i == jj ? 1.f : 0.f);
  }
  __syncthreads();
  for (int t = 9; t >= 1; --t){
    mm64(Bs, Xs, Cs, tid);
    __syncthreads();
    const float invt = 1.f / (float)t;
    for (int idx = tid; idx < DD*DD; idx += 1024){
      const int i = idx >> 6, jj = idx & 63;
      Xs[i*65 + jj] = Cs[i*65 + jj]*invt + (i == jj ? 1.f : 0.f);
    }
    __syncthreads();
  }
  for (int r = 0; r < sq; ++r){
    mm64(Xs, Xs, Cs, tid);
    __syncthreads();
    for (int idx = tid; idx < DD*DD; idx += 1024){
      const int i = idx >> 6, jj = idx & 63;
      Xs[i*65 + jj] = Cs[i*65 + jj];
    }
    __syncthreads();
  }
  for (int idx = tid; idx < DD*DD; idx += 1024){
    const int i = idx >> 6, jj = idx & 63;
    M[b*DD*DD + idx] = Xs[i*65 + jj] - (i == jj ? 1.f : 0.f);
  }
}

// ---------------- K6: w = (x @ U) @ M, 64-row tiles ----------------
__global__ __launch_bounds__(256) void k_zw(const float* __restrict__ x, const float* __restrict__ U,
                                            const float* __restrict__ Mg, float* __restrict__ wbuf){
  __shared__ float xs[64*33];
  __shared__ float Us[32*65];
  __shared__ float zs[64*65];
  __shared__ float Ms[64*65];
  const int tid = threadIdx.x;
  const int row0 = blockIdx.x * 64;
  const int bb = row0 >> 10;
  const int tx = tid & 15, ty = tid >> 4;
  const int kk = tid & 31, lr = tid >> 5;
  const int du = tid & 63, ku = tid >> 6;
  float acc[4][4];
  #pragma unroll
  for (int i=0;i<4;++i){
    #pragma unroll
    for (int jq=0;jq<4;++jq) acc[i][jq]=0.f;
  }
  for (int kc = 0; kc < NN; kc += 32){
    __syncthreads();
    #pragma unroll
    for (int ii = 0; ii < 8; ++ii)
      xs[(lr + 8*ii)*33 + kk] = x[(row0 + lr + 8*ii)*NN + kc + kk];
    #pragma unroll
    for (int ii = 0; ii < 8; ++ii)
      Us[(ku + 4*ii)*65 + du] = U[(kc + ku + 4*ii)*DD + du];
    __syncthreads();
    #pragma unroll 4
    for (int k = 0; k < 32; ++k){
      float a[4], bv[4];
      #pragma unroll
      for (int i=0;i<4;++i) a[i] = xs[(ty*4+i)*33 + k];
      #pragma unroll
      for (int jq=0;jq<4;++jq) bv[jq] = Us[k*65 + tx*4 + jq];
      #pragma unroll
      for (int i=0;i<4;++i){
        #pragma unroll
        for (int jq=0;jq<4;++jq) acc[i][jq] = fmaf(a[i], bv[jq], acc[i][jq]);
      }
    }
  }
  __syncthreads();
  #pragma unroll
  for (int i=0;i<4;++i){
    #pragma unroll
    for (int jq=0;jq<4;++jq) zs[(ty*4+i)*65 + tx*4 + jq] = acc[i][jq];
  }
  #pragma unroll
  for (int ii = 0; ii < 16; ++ii)
    Ms[(ku + 4*ii)*65 + du] = Mg[bb*4096 + (ku + 4*ii)*DD + du];
  __syncthreads();
  #pragma unroll
  for (int i=0;i<4;++i){
    #pragma unroll
    for (int jq=0;jq<4;++jq) acc[i][jq]=0.f;
  }
  for (int d = 0; d < DD; ++d){
    float a[4], bv[4];
    #pragma unroll
    for (int i=0;i<4;++i) a[i] = zs[(ty*4+i)*65 + d];
    #pragma unroll
    for (int jq=0;jq<4;++jq) bv[jq] = Ms[d*65 + tx*4 + jq];
    #pragma unroll
    for (int i=0;i<4;++i){
      #pragma unroll
      for (int jq=0;jq<4;++jq) acc[i][jq] = fmaf(a[i], bv[jq], acc[i][jq]);
    }
  }
  #pragma unroll
  for (int i=0;i<4;++i){
    float4 wv = make_float4(acc[i][0], acc[i][1], acc[i][2], acc[i][3]);
    *(float4*)&wbuf[(row0 + ty*4 + i)*DD + tx*4] = wv;
  }
}

// ---------------- K7: out = x + w @ U^T ----------------
__global__ __launch_bounds__(256) void k_out(const float* __restrict__ x, const float* __restrict__ wbuf,
                                             const float* __restrict__ U, float* __restrict__ out){
  __shared__ float wts[64*65];
  __shared__ float Ut[64*65];
  const int tid = threadIdx.x;
  const int n0 = blockIdx.x * 64;
  const int row0 = blockIdx.y * 64;
  const int tx = tid & 15, ty = tid >> 4;
  const int du = tid & 63, ku = tid >> 6;
  #pragma unroll
  for (int ii = 0; ii < 16; ++ii){
    wts[(ku + 4*ii)*65 + du] = wbuf[(row0 + ku + 4*ii)*DD + du];
    Ut[(ku + 4*ii)*65 + du]  = U[(n0 + ku + 4*ii)*DD + du];
  }
  __syncthreads();
  float acc[4][4];
  #pragma unroll
  for (int i=0;i<4;++i){
    #pragma unroll
    for (int jq=0;jq<4;++jq) acc[i][jq]=0.f;
  }
  for (int d = 0; d < DD; ++d){
    float a[4], bv[4];
    #pragma unroll
    for (int i=0;i<4;++i) a[i] = wts[(ty*4+i)*65 + d];
    #pragma unroll
    for (int jq=0;jq<4;++jq) bv[jq] = Ut[(tx*4+jq)*65 + d];
    #pragma unroll
    for (int i=0;i<4;++i){
      #pragma unroll
      for (int jq=0;jq<4;++jq) acc[i][jq] = fmaf(a[i], bv[jq], acc[i][jq]);
    }
  }
  #pragma unroll
  for (int i = 0; i < 4; ++i){
    const int r = row0 + ty*4 + i;
    const float4 xv = *(const float4*)&x[r*NN + n0 + tx*4];
    float4 ov;
    ov.x = xv.x + acc[i][0];
    ov.y = xv.y + acc[i][1];
    ov.z = xv.z + acc[i][2];
    ov.w = xv.w + acc[i][3];
    *(float4*)&out[r*NN + n0 + tx*4] = ov;
  }
}

extern "C" void kernel_launch(void* const* d_in, const int* in_sizes, int n_in,
                              void* d_out, int out_size, void* d_ws, size_t ws_size,
                              hipStream_t stream) {
  const float* x    = (const float*)d_in[0];
  const float* cond = (const float*)d_in[1];
  const float* P    = (const float*)d_in[2];
  const float* W    = (const float*)d_in[3];
  const float* bias = (const float*)d_in[4];
  float* out = (float*)d_out;
  float* ws  = (float*)d_ws;

  float* U     = ws;               // 73728
  float* Gpart = ws + 73728;       // 18*4096 = 73728
  float* Rbuf  = ws + 147456;      // 4096
  float* v     = ws + 151552;      // 32256
  float* M     = ws + 183808;      // 65536
  float* wbuf  = ws + 249344;      // 1048576

  hipLaunchKernelGGL(k_gram,   dim3(GPARTS),   dim3(256), 0, stream, P, Gpart);
  hipLaunchKernelGGL(k_vproj,  dim3(NSK),      dim3(256), 0, stream, cond, W, bias, v);
  hipLaunchKernelGGL(k_qr,     dim3(1),        dim3(256), 0, stream, Gpart, P, Rbuf);
  hipLaunchKernelGGL(k_solveU, dim3(NN/DD),    dim3(64),  0, stream, P, Rbuf, U);
  hipLaunchKernelGGL(k_expm,   dim3(NB),       dim3(1024),0, stream, v, M);
  hipLaunchKernelGGL(k_zw,     dim3(NROWS/64), dim3(256), 0, stream, x, U, M, wbuf);
  hipLaunchKernelGGL(k_out,    dim3(NN/64, NROWS/64), dim3(256), 0, stream, x, wbuf, U, out);
}

// Round 4
// 285.220 us; speedup vs baseline: 3.1028x; 1.6566x over previous
//
#include <hip/hip_runtime.h>
#include <math.h>

#define NN 1152
#define DD 64
#define NSK 2016
#define NB 16
#define NROWS (NB*1024)
#define GPARTS 6

typedef short bf16x8 __attribute__((ext_vector_type(8)));
typedef float f32x4  __attribute__((ext_vector_type(4)));

__device__ __forceinline__ short bfr(float f){
  unsigned u = __float_as_uint(f);
  u += 0x7fffu + ((u >> 16) & 1u);
  return (short)(u >> 16);
}

// ================= K1: combined vproj (blocks 0..2015) + partial gram (blocks 2016..2021) ==========
__global__ __launch_bounds__(256) void k_pre(const float* __restrict__ cond, const float* __restrict__ W,
                                             const float* __restrict__ bias, float* __restrict__ v,
                                             const float* __restrict__ P, float* __restrict__ Gpart){
  __shared__ float Ps[64*68];
  __shared__ float red[256*17];
  const int tid = threadIdx.x;
  if (blockIdx.x < NSK){
    // ---- vproj: v[b][q] = silu(cond[b]) . W[q] + bias[q]
    const int q = blockIdx.x;
    float acc[NB];
    #pragma unroll
    for (int b = 0; b < NB; ++b) acc[b] = 0.f;
    for (int c = tid; c < NN; c += 256){
      const float wv = W[q*NN + c];
      #pragma unroll
      for (int b = 0; b < NB; ++b){
        const float xv = cond[b*NN + c];
        const float s = xv / (1.f + __expf(-xv));
        acc[b] = fmaf(wv, s, acc[b]);
      }
    }
    #pragma unroll
    for (int b = 0; b < NB; ++b) red[tid*17 + b] = acc[b];
    __syncthreads();
    for (int off = 128; off > 0; off >>= 1){
      if (tid < off){
        #pragma unroll
        for (int b = 0; b < NB; ++b) red[tid*17 + b] += red[(tid+off)*17 + b];
      }
      __syncthreads();
    }
    if (tid < NB) v[tid*NSK + q] = red[tid] + bias[q];
  } else {
    // ---- partial gram: block p covers rows p*192 .. p*192+191 (3 chunks of 64)
    const int p = blockIdx.x - NSK;
    const int lr = tid >> 4, lc = (tid & 15) * 4;
    const int ti = tid >> 4, tj = tid & 15;
    float acc[4][4];
    #pragma unroll
    for (int i=0;i<4;++i){
      #pragma unroll
      for (int j=0;j<4;++j) acc[i][j]=0.f;
    }
    for (int ch = 0; ch < 3; ++ch){
      const int n0 = p*192 + ch*64;
      __syncthreads();
      #pragma unroll
      for (int ii = 0; ii < 4; ++ii){
        const float4 pv = *(const float4*)&P[(n0 + lr + 16*ii)*DD + lc];
        *(float4*)&Ps[(lr + 16*ii)*68 + lc] = pv;
      }
      __syncthreads();
      for (int r = 0; r < 64; ++r){
        const float4 a = *(const float4*)&Ps[r*68 + ti*4];
        const float4 b = *(const float4*)&Ps[r*68 + tj*4];
        const float av[4] = {a.x,a.y,a.z,a.w};
        const float bv[4] = {b.x,b.y,b.z,b.w};
        #pragma unroll
        for (int i=0;i<4;++i){
          #pragma unroll
          for (int j=0;j<4;++j) acc[i][j] = fmaf(av[i], bv[j], acc[i][j]);
        }
      }
    }
    float* g = &Gpart[p*DD*DD];
    #pragma unroll
    for (int i=0;i<4;++i){
      float4 ov = make_float4(acc[i][0], acc[i][1], acc[i][2], acc[i][3]);
      *(float4*)&g[(ti*4+i)*DD + tj*4] = ov;
    }
  }
}

// ================= K2: combined register-wave QR (block 16) + expm (blocks 0..15) ==========
__device__ void qr_wave(const float* __restrict__ Gpart, const float* __restrict__ P,
                        float* __restrict__ Rout){
  const int j = threadIdx.x; // lane = column j
  float Gc[DD], Wc[DD], Rc[DD];
  #pragma unroll
  for (int i = 0; i < DD; ++i){
    float g = 0.f;
    #pragma unroll
    for (int p = 0; p < GPARTS; ++p) g += Gpart[p*4096 + i*DD + j];
    Gc[i] = g;
    Wc[i] = P[i*DD + j];
  }
  #pragma unroll
  for (int k = 0; k < DD; ++k){
    const float gkk = __shfl(Gc[k], k);
    const float wkk = __shfl(Wc[k], k);
    const float beta = (wkk >= 0.f) ? -sqrtf(gkk) : sqrtf(gkk);
    const float wkj = Wc[k];
    const float dj  = Gc[k] - beta*wkj;
    const float cj  = dj / (beta*(beta - wkk));
    float rkj = wkj + dj/beta;
    if (j == k) rkj = beta;
    if (j <  k) rkj = 0.f;
    Rc[k] = rkj;
    #pragma unroll
    for (int i = k+1; i < DD; ++i){
      const float wik = __shfl(Wc[i], k);   // column k of Wt lives in lane k
      const float rki = __shfl(rkj, i);     // R[k][i] lives in lane i
      Wc[i] = fmaf(-cj,  wik, Wc[i]);
      Gc[i] = fmaf(-rki, rkj, Gc[i]);
    }
  }
  #pragma unroll
  for (int i = 0; i < DD; ++i) Rout[i*DD + j] = Rc[i];
}

__device__ __forceinline__ void mmul68(const float* __restrict__ A, const float* __restrict__ B,
                                       float* __restrict__ C, int tid){
  __syncthreads();
  const int ty = tid >> 4, tx = tid & 15;
  float acc[4][4];
  #pragma unroll
  for (int i=0;i<4;++i){
    #pragma unroll
    for (int j=0;j<4;++j) acc[i][j]=0.f;
  }
  for (int kq = 0; kq < 16; ++kq){
    float4 a[4], b[4];
    #pragma unroll
    for (int i=0;i<4;++i) a[i] = *(const float4*)&A[(ty*4+i)*68 + kq*4];
    #pragma unroll
    for (int kk=0;kk<4;++kk) b[kk] = *(const float4*)&B[(kq*4+kk)*68 + tx*4];
    #pragma unroll
    for (int i=0;i<4;++i){
      const float av[4] = {a[i].x, a[i].y, a[i].z, a[i].w};
      #pragma unroll
      for (int kk=0;kk<4;++kk){
        acc[i][0] = fmaf(av[kk], b[kk].x, acc[i][0]);
        acc[i][1] = fmaf(av[kk], b[kk].y, acc[i][1]);
        acc[i][2] = fmaf(av[kk], b[kk].z, acc[i][2]);
        acc[i][3] = fmaf(av[kk], b[kk].w, acc[i][3]);
      }
    }
  }
  #pragma unroll
  for (int i=0;i<4;++i)
    *(float4*)&C[(ty*4+i)*68 + tx*4] = make_float4(acc[i][0],acc[i][1],acc[i][2],acc[i][3]);
  __syncthreads();
}

__global__ __launch_bounds__(256,1) void k_setup(const float* __restrict__ Gpart, const float* __restrict__ P,
                                                 float* __restrict__ Rout,
                                                 const float* __restrict__ v, float* __restrict__ Mg){
  __shared__ float Bs[64*68], B2[64*68], B3[64*68], Tb[64*68], Xb[64*68];
  __shared__ float ncol[DD];
  __shared__ float scl_s;
  __shared__ int   ssh_s;
  const int tid = threadIdx.x;
  if (blockIdx.x == NB){
    if (tid >= 64) return;
    qr_wave(Gpart, P, Rout);
    return;
  }
  const int b = blockIdx.x;
  // build skew A (unscaled) into Xb
  for (int idx = tid; idx < 64*64; idx += 256)
    Xb[(idx>>6)*68 + (idx&63)] = 0.f;
  __syncthreads();
  for (int idx = tid; idx < NSK; idx += 256){
    int i = (int)((127.0f - sqrtf(16129.0f - 8.0f*(float)idx)) * 0.5f);
    while (i*(127 - i)/2 > idx) --i;
    while ((i+1)*(127 - (i+1))/2 <= idx) ++i;
    const int jj = idx - i*(127 - i)/2 + i + 1;
    const float val = v[b*NSK + idx];
    Xb[i*68 + jj] = val;
    Xb[jj*68 + i] = -val;
  }
  __syncthreads();
  if (tid < DD){
    float s = 0.f;
    for (int r = 0; r < DD; ++r) s += fabsf(Xb[r*68 + tid]);
    ncol[tid] = s;
  }
  __syncthreads();
  if (tid == 0){
    float nrm = 0.f;
    for (int c = 0; c < DD; ++c) nrm = fmaxf(nrm, ncol[c]);
    int s = 0; float scale = 1.f;
    while (nrm > 1.0f && s < 40){ nrm *= 0.5f; scale *= 0.5f; ++s; }
    ssh_s = s; scl_s = scale;
  }
  __syncthreads();
  const float scale = scl_s;
  const int   sq    = ssh_s;
  for (int idx = tid; idx < 64*64; idx += 256){
    const int i = idx>>6, jj = idx&63;
    Bs[i*68 + jj] = Xb[i*68 + jj] * scale;
  }
  // B2 = B*B ; B3 = B2*B
  mmul68(Bs, Bs, B2, tid);
  mmul68(B2, Bs, B3, tid);
  // T = G2 + c9*B3 ; G2 = I/720 + B/5040 + B2/40320
  for (int idx = tid; idx < 64*64; idx += 256){
    const int i = idx>>6, jj = idx&63;
    const int o = i*68 + jj;
    Tb[o] = (i==jj ? (1.f/720.f) : 0.f) + Bs[o]*(1.f/5040.f) + B2[o]*(1.f/40320.f) + B3[o]*(1.f/362880.f);
  }
  mmul68(B3, Tb, Xb, tid);              // X = B3*T
  for (int idx = tid; idx < 64*64; idx += 256){
    const int i = idx>>6, jj = idx&63;
    const int o = i*68 + jj;
    Xb[o] += (i==jj ? (1.f/6.f) : 0.f) + Bs[o]*(1.f/24.f) + B2[o]*(1.f/120.f);
  }
  mmul68(B3, Xb, Tb, tid);              // T = B3*X
  for (int idx = tid; idx < 64*64; idx += 256){
    const int i = idx>>6, jj = idx&63;
    const int o = i*68 + jj;
    Tb[o] += (i==jj ? 1.f : 0.f) + Bs[o] + B2[o]*0.5f;   // + G0
  }
  // squarings
  float* cur = Tb;
  float* oth = Xb;
  for (int r = 0; r < sq; ++r){
    mmul68(cur, cur, oth, tid);
    float* t = cur; cur = oth; oth = t;
  }
  for (int idx = tid; idx < 64*64; idx += 256){
    const int i = idx>>6, jj = idx&63;
    Mg[b*4096 + idx] = cur[i*68 + jj] - (i==jj ? 1.f : 0.f);
  }
}

// ================= K3: solve u.R = p per row; emit U bf16 (row-major) + U^T bf16 ==========
__global__ __launch_bounds__(64) void k_solveU(const float* __restrict__ P, const float* __restrict__ Rg,
                                               short* __restrict__ Ubf, short* __restrict__ Utbf){
  __shared__ float Rs[DD*DD];
  __shared__ float Ps[DD*65];
  __shared__ float rd[DD];
  const int tid = threadIdx.x;
  const int n0 = blockIdx.x * DD;
  for (int r = 0; r < DD; ++r){
    Rs[r*DD + tid] = Rg[r*DD + tid];
    Ps[r*65 + tid] = P[(n0 + r)*DD + tid];
  }
  rd[tid] = 1.f / Rg[tid*DD + tid];
  __syncthreads();
  float u[DD];
  #pragma unroll
  for (int j = 0; j < DD; ++j){
    float s0 = Ps[tid*65 + j], s1 = 0.f;
    #pragma unroll
    for (int l = 0; l + 1 < j; l += 2){
      s0 = fmaf(-u[l],   Rs[l*DD + j],     s0);
      s1 = fmaf(-u[l+1], Rs[(l+1)*DD + j], s1);
    }
    if (j & 1) s0 = fmaf(-u[j-1], Rs[(j-1)*DD + j], s0);
    u[j] = (s0 + s1) * rd[j];
  }
  // U^T bf16 [64][1152]: coalesced per d
  #pragma unroll
  for (int d = 0; d < DD; ++d)
    Utbf[d*NN + n0 + tid] = bfr(u[d]);
  // U bf16 row-major [1152][64]: per-lane 16B vector stores of own row
  #pragma unroll
  for (int j8 = 0; j8 < 8; ++j8){
    bf16x8 pk;
    #pragma unroll
    for (int jj = 0; jj < 8; ++jj) pk[jj] = bfr(u[j8*8 + jj]);
    *(bf16x8*)&Ubf[(n0 + tid)*DD + j8*8] = pk;
  }
}

// ================= K4: fused main: z = x.U ; w = z.(R-I) ; out = x + w.U^T ==========
__global__ __launch_bounds__(512,1) void k_main(const float* __restrict__ x, const short* __restrict__ Ubf,
                                                const short* __restrict__ Utbf, const float* __restrict__ Mg,
                                                float* __restrict__ out){
  __shared__ float zs[64*68];
  __shared__ float Ms[64*68];
  __shared__ short wbf[64*72];
  const int tid  = threadIdx.x;
  const int lane = tid & 63, wid = tid >> 6;
  const int row0 = blockIdx.x * 64;
  const int bb   = row0 >> 10;
  const int m    = lane & 15, quad = lane >> 4;
  // stage M = (R-I) for this batch
  for (int idx = tid; idx < 64*64; idx += 512)
    Ms[(idx>>6)*68 + (idx&63)] = Mg[bb*4096 + idx];

  // ---- phase 1: z = x_tile @ U   (wave: rows (wid&3)*16, cols (wid>>2)*32)
  const int r0 = (wid & 3) * 16;
  const int c0 = (wid >> 2) * 32;
  f32x4 acc0 = {0.f,0.f,0.f,0.f}, acc1 = {0.f,0.f,0.f,0.f};
  const float* xrow = &x[(row0 + r0 + m)*NN + quad*8];
  const short* ut0  = &Utbf[(c0      + m)*NN + quad*8];
  const short* ut1  = &Utbf[(c0 + 16 + m)*NN + quad*8];
  float4 xa = *(const float4*)(xrow);
  float4 xb = *(const float4*)(xrow + 4);
  bf16x8 b0 = *(const bf16x8*)(ut0);
  bf16x8 b1 = *(const bf16x8*)(ut1);
  for (int kc = 0; kc < NN; kc += 32){
    float4 nxa, nxb; bf16x8 nb0, nb1;
    if (kc + 32 < NN){
      nxa = *(const float4*)(xrow + kc + 32);
      nxb = *(const float4*)(xrow + kc + 36);
      nb0 = *(const bf16x8*)(ut0 + kc + 32);
      nb1 = *(const bf16x8*)(ut1 + kc + 32);
    }
    bf16x8 a;
    a[0]=bfr(xa.x); a[1]=bfr(xa.y); a[2]=bfr(xa.z); a[3]=bfr(xa.w);
    a[4]=bfr(xb.x); a[5]=bfr(xb.y); a[6]=bfr(xb.z); a[7]=bfr(xb.w);
    acc0 = __builtin_amdgcn_mfma_f32_16x16x32_bf16(a, b0, acc0, 0, 0, 0);
    acc1 = __builtin_amdgcn_mfma_f32_16x16x32_bf16(a, b1, acc1, 0, 0, 0);
    xa = nxa; xb = nxb; b0 = nb0; b1 = nb1;
  }
  // z -> LDS (C-layout: col = lane&15, row = quad*4+reg)
  #pragma unroll
  for (int q = 0; q < 4; ++q){
    zs[(r0 + quad*4 + q)*68 + c0      + m] = acc0[q];
    zs[(r0 + quad*4 + q)*68 + c0 + 16 + m] = acc1[q];
  }
  __syncthreads();

  // ---- phase 2: w = z @ M (fp32), store bf16
  {
    const int r  = tid >> 3;
    const int cc = (tid & 7) * 8;
    float w0[8];
    #pragma unroll
    for (int jj = 0; jj < 8; ++jj) w0[jj] = 0.f;
    for (int k = 0; k < 64; ++k){
      const float zr = zs[r*68 + k];
      const float4 m0 = *(const float4*)&Ms[k*68 + cc];
      const float4 m1 = *(const float4*)&Ms[k*68 + cc + 4];
      w0[0] = fmaf(zr, m0.x, w0[0]); w0[1] = fmaf(zr, m0.y, w0[1]);
      w0[2] = fmaf(zr, m0.z, w0[2]); w0[3] = fmaf(zr, m0.w, w0[3]);
      w0[4] = fmaf(zr, m1.x, w0[4]); w0[5] = fmaf(zr, m1.y, w0[5]);
      w0[6] = fmaf(zr, m1.z, w0[6]); w0[7] = fmaf(zr, m1.w, w0[7]);
    }
    bf16x8 pk;
    #pragma unroll
    for (int jj = 0; jj < 8; ++jj) pk[jj] = bfr(w0[jj]);
    *(bf16x8*)&wbf[r*72 + cc] = pk;
  }
  __syncthreads();

  // ---- phase 3: out = x + w @ U^T  (wave: rows (wid&3)*16; col-tiles (wid>>2)+2*it)
  bf16x8 wa0 = *(const bf16x8*)&wbf[(r0 + m)*72 +      quad*8];
  bf16x8 wa1 = *(const bf16x8*)&wbf[(r0 + m)*72 + 32 + quad*8];
  const int colpar = wid >> 2;
  for (int it = 0; it < 36; ++it){
    const int n0 = (colpar + 2*it) * 16;
    bf16x8 ub0 = *(const bf16x8*)&Ubf[(n0 + m)*DD +      quad*8];
    bf16x8 ub1 = *(const bf16x8*)&Ubf[(n0 + m)*DD + 32 + quad*8];
    f32x4 acc = {0.f,0.f,0.f,0.f};
    acc = __builtin_amdgcn_mfma_f32_16x16x32_bf16(wa0, ub0, acc, 0, 0, 0);
    acc = __builtin_amdgcn_mfma_f32_16x16x32_bf16(wa1, ub1, acc, 0, 0, 0);
    #pragma unroll
    for (int q = 0; q < 4; ++q){
      const int r = row0 + r0 + quad*4 + q;
      const int c = n0 + m;
      out[r*NN + c] = x[r*NN + c] + acc[q];
    }
  }
}

extern "C" void kernel_launch(void* const* d_in, const int* in_sizes, int n_in,
                              void* d_out, int out_size, void* d_ws, size_t ws_size,
                              hipStream_t stream) {
  const float* x    = (const float*)d_in[0];
  const float* cond = (const float*)d_in[1];
  const float* P    = (const float*)d_in[2];
  const float* W    = (const float*)d_in[3];
  const float* bias = (const float*)d_in[4];
  float* out = (float*)d_out;
  float* ws  = (float*)d_ws;

  float* Gpart = ws;               // 6*4096 = 24576
  float* Rbuf  = ws + 24576;       // 4096
  float* vbuf  = ws + 28672;       // 32256
  float* Mg    = ws + 61440;       // 65536
  short* Ubf   = (short*)(ws + 126976);   // 1152*64 bf16
  short* Utbf  = (short*)(ws + 163840);   // 64*1152 bf16

  hipLaunchKernelGGL(k_pre,   dim3(NSK + GPARTS), dim3(256), 0, stream, cond, W, bias, vbuf, P, Gpart);
  hipLaunchKernelGGL(k_setup, dim3(NB + 1),       dim3(256), 0, stream, Gpart, P, Rbuf, vbuf, Mg);
  hipLaunchKernelGGL(k_solveU,dim3(NN/DD),        dim3(64),  0, stream, P, Rbuf, Ubf, Utbf);
  hipLaunchKernelGGL(k_main,  dim3(NROWS/64),     dim3(512), 0, stream, x, Ubf, Utbf, Mg, out);
}